// Round 14
// baseline (153.722 us; speedup 1.0000x reference)
//
#include <hip/hip_runtime.h>
#include <math.h>

#define C_IN  128
#define C_HID 64
#define C_OUT 40

#define BKT_SH 7
#define BKT_N  (1 << BKT_SH)          // 128 nodes per bucket
#define CHUNK  1024                   // edges per hist/binA block
#define EPT    (CHUNK / 256)          // 4 edges per thread

__device__ __forceinline__ float bfLO(unsigned int u) { return __uint_as_float(u << 16); }
__device__ __forceinline__ float bfHI(unsigned int u) { return __uint_as_float(u & 0xFFFF0000u); }
__device__ __forceinline__ unsigned short f2bf(float f) {   // round-to-nearest-even
    unsigned int x = __float_as_uint(f);
    return (unsigned short)((x + 0x7FFFu + ((x >> 16) & 1u)) >> 16);
}

// ---------------- pass 0: per-chunk, per-bucket histogram ----------------
__global__ void k_hist(const int* __restrict__ dst, int* __restrict__ hist2d, int e, int nbkt) {
    __shared__ int hist[512];
    for (int i = threadIdx.x; i < nbkt; i += 256) hist[i] = 0;
    __syncthreads();
    int base = blockIdx.x * CHUNK;
#pragma unroll
    for (int j = 0; j < EPT; ++j) {
        int i = base + j * 256 + threadIdx.x;
        if (i < e) atomicAdd(&hist[dst[i] >> BKT_SH], 1);
    }
    __syncthreads();
    int* row = hist2d + (size_t)blockIdx.x * nbkt;
    for (int i = threadIdx.x; i < nbkt; i += 256) row[i] = hist[i];
}

// ---------------- per-bucket scan over chunks (looped, carry) ----------------
__global__ void k_bktscan(const int* __restrict__ hist2d, int* __restrict__ base2d,
                          int* __restrict__ tot, int nchunks, int nbkt) {
    __shared__ int wtot[4];
    const int b = blockIdx.x;
    const int t = threadIdx.x;
    const int lane = t & 63, wv = t >> 6;
    int carry = 0;
    for (int c0 = 0; c0 < nchunks; c0 += 256) {
        int c = c0 + t;
        int v = (c < nchunks) ? hist2d[(size_t)c * nbkt + b] : 0;
        int inc = v;
        for (int o = 1; o < 64; o <<= 1) { int u = __shfl_up(inc, o); if (lane >= o) inc += u; }
        if (lane == 63) wtot[wv] = inc;
        __syncthreads();
        int add = carry;
        for (int k = 0; k < wv; ++k) add += wtot[k];
        if (c < nchunks) base2d[(size_t)c * nbkt + b] = add + inc - v;
        carry += wtot[0] + wtot[1] + wtot[2] + wtot[3];
        __syncthreads();
    }
    if (t == 0) tot[b] = carry;
}

// ---------------- scan over bucket totals -> bstart ----------------
__global__ void k_scan_bkt(const int* __restrict__ tot, int* __restrict__ bstart, int nbkt, int e) {
    __shared__ int wtot[4];
    const int t = threadIdx.x;
    const int lane = t & 63, wv = t >> 6;
    int carry = 0;
    for (int b0 = 0; b0 < nbkt; b0 += 256) {
        int b = b0 + t;
        int v = (b < nbkt) ? tot[b] : 0;
        int inc = v;
        for (int o = 1; o < 64; o <<= 1) { int u = __shfl_up(inc, o); if (lane >= o) inc += u; }
        if (lane == 63) wtot[wv] = inc;
        __syncthreads();
        int add = carry;
        for (int k = 0; k < wv; ++k) add += wtot[k];
        if (b < nbkt) bstart[b] = add + inc - v;
        carry += wtot[0] + wtot[1] + wtot[2] + wtot[3];
        __syncthreads();
    }
    if (t == 0) bstart[nbkt] = e;
}

// ---------------- pass A: LDS multisplit by bucket ----------------
__global__ void k_binA(const int* __restrict__ src, const int* __restrict__ dst,
                       const int* __restrict__ bstart, const int* __restrict__ hist2d,
                       const int* __restrict__ base2d, unsigned int* __restrict__ bpack,
                       int e, int nbkt) {
    __shared__ int hist[512];
    __shared__ int excl[512];
    __shared__ int gbase[512];
    __shared__ int wtot[4];
    __shared__ unsigned int stage[CHUNK];
    const int t = threadIdx.x;
    const int base = blockIdx.x * CHUNK;
    const int lane = t & 63, wv = t >> 6;

    int carry = 0;
    for (int b0 = 0; b0 < nbkt; b0 += 256) {
        int b = b0 + t;
        int v = (b < nbkt) ? hist2d[(size_t)blockIdx.x * nbkt + b] : 0;
        int inc = v;
        for (int o = 1; o < 64; o <<= 1) { int u = __shfl_up(inc, o); if (lane >= o) inc += u; }
        if (lane == 63) wtot[wv] = inc;
        __syncthreads();
        int add = carry;
        for (int k = 0; k < wv; ++k) add += wtot[k];
        if (b < nbkt) {
            excl[b]  = add + inc - v;
            hist[b]  = 0;
            gbase[b] = bstart[b] + base2d[(size_t)blockIdx.x * nbkt + b];
        }
        carry += wtot[0] + wtot[1] + wtot[2] + wtot[3];
        __syncthreads();
    }

#pragma unroll
    for (int j = 0; j < EPT; ++j) {
        int i = base + j * 256 + t;
        if (i < e) {
            int d = dst[i];
            unsigned int pk = (unsigned int)src[i] | ((unsigned int)d << 16);   // N < 65536
            int bk = d >> BKT_SH;
            int p  = excl[bk] + atomicAdd(&hist[bk], 1);
            stage[p] = pk;
        }
    }
    __syncthreads();

    int nchunk = min(CHUNK, e - base);
    for (int i = t; i < nchunk; i += 256) {
        unsigned int u = stage[i];
        int b = (int)(u >> 16) >> BKT_SH;
        bpack[gbase[b] + (i - excl[b])] = u;
    }
}

// ---------------- pass B: per-bucket counting sort ----------------
__global__ void k_binB(const int* __restrict__ bstart, const unsigned int* __restrict__ bpack,
                       int* __restrict__ row_start, float* __restrict__ dinv,
                       int* __restrict__ csr_src, int n, int e, int nbkt) {
    __shared__ int hist[BKT_N];
    __shared__ int excl[BKT_N];
    __shared__ int wtot[4];
    const int t = threadIdx.x;
    const int b = blockIdx.x;
    const int beg = bstart[b], end = bstart[b + 1];
    const int nodebase = b << BKT_SH;
    const int nloc = min(BKT_N, n - nodebase);

    for (int i = t; i < nloc; i += 256) hist[i] = 0;
    __syncthreads();
    for (int i = beg + t; i < end; i += 256)
        atomicAdd(&hist[(int)(bpack[i] >> 16) - nodebase], 1);
    __syncthreads();

    {
        int idx = t;
        int v = (idx < nloc) ? hist[idx] : 0;
        int inc = v; int lane = t & 63; int wv = t >> 6;
        for (int o = 1; o < 64; o <<= 1) { int u = __shfl_up(inc, o); if (lane >= o) inc += u; }
        if (lane == 63) wtot[wv] = inc;
        __syncthreads();
        int add = 0;
        for (int k = 0; k < wv; ++k) add += wtot[k];
        if (idx < nloc) excl[idx] = add + inc - v;
    }
    __syncthreads();

    for (int i = t; i < nloc; i += 256) {
        row_start[nodebase + i] = beg + excl[i];
        dinv[nodebase + i] = rsqrtf((float)hist[i] + 1.0f);   // +1 self loop
    }
    if (b == nbkt - 1 && t == 0) row_start[n] = e;
    __syncthreads();
    for (int i = t; i < nloc; i += 256) hist[i] = 0;   // reuse as cursors
    __syncthreads();

    for (int i = beg + t; i < end; i += 256) {
        unsigned int u = bpack[i];
        int dl = (int)(u >> 16) - nodebase;
        int p = beg + excl[dl] + atomicAdd(&hist[dl], 1);
        csr_src[p] = (int)(u & 0xFFFFu);
    }
}

// ---------------- GEMM1 -> two compact channel-half arrays (each 3.2 MB) ----------------
__global__ void k_gemm1(const float* __restrict__ X, const float* __restrict__ W1,
                        const float* __restrict__ dinv,
                        unsigned short* __restrict__ h1lo, unsigned short* __restrict__ h1hi, int n) {
    __shared__ float xt[C_IN][64];
    __shared__ float wl[C_IN * C_HID];
    const int t = threadIdx.x;
    const int row0 = blockIdx.x * 64;

    for (int i = t; i < C_IN * C_HID; i += 256) wl[i] = W1[i];
    {
        int r = t >> 2, q = t & 3;
        int grow = row0 + r;
        for (int j = 0; j < 8; ++j) {
            int k = q * 32 + j * 4;
            float4 v = make_float4(0.f, 0.f, 0.f, 0.f);
            if (grow < n) v = *(const float4*)(X + (size_t)grow * C_IN + k);
            xt[k + 0][r] = v.x; xt[k + 1][r] = v.y; xt[k + 2][r] = v.z; xt[k + 3][r] = v.w;
        }
    }
    __syncthreads();

    const int rg = t >> 4, cg = t & 15;
    const int r0 = rg * 4, c0 = cg * 4;
    float acc[4][4] = {};
#pragma unroll 4
    for (int k = 0; k < C_IN; ++k) {
        float4 a = *(const float4*)&xt[k][r0];
        float4 b = *(const float4*)&wl[k * C_HID + c0];
        acc[0][0] = fmaf(a.x, b.x, acc[0][0]); acc[0][1] = fmaf(a.x, b.y, acc[0][1]);
        acc[0][2] = fmaf(a.x, b.z, acc[0][2]); acc[0][3] = fmaf(a.x, b.w, acc[0][3]);
        acc[1][0] = fmaf(a.y, b.x, acc[1][0]); acc[1][1] = fmaf(a.y, b.y, acc[1][1]);
        acc[1][2] = fmaf(a.y, b.z, acc[1][2]); acc[1][3] = fmaf(a.y, b.w, acc[1][3]);
        acc[2][0] = fmaf(a.z, b.x, acc[2][0]); acc[2][1] = fmaf(a.z, b.y, acc[2][1]);
        acc[2][2] = fmaf(a.z, b.z, acc[2][2]); acc[2][3] = fmaf(a.z, b.w, acc[2][3]);
        acc[3][0] = fmaf(a.w, b.x, acc[3][0]); acc[3][1] = fmaf(a.w, b.y, acc[3][1]);
        acc[3][2] = fmaf(a.w, b.z, acc[3][2]); acc[3][3] = fmaf(a.w, b.w, acc[3][3]);
    }
#pragma unroll
    for (int i = 0; i < 4; ++i) {
        int row = row0 + r0 + i;
        if (row < n) {
            float di = dinv[row];
            ushort4 o;
            o.x = f2bf(di * acc[i][0]); o.y = f2bf(di * acc[i][1]);
            o.z = f2bf(di * acc[i][2]); o.w = f2bf(di * acc[i][3]);
            if (c0 < 32) *(ushort4*)(h1lo + (size_t)row * 32 + c0)        = o;
            else         *(ushort4*)(h1hi + (size_t)row * 32 + (c0 - 32)) = o;
        }
    }
}

// ------- layer-1 aggregate half-pass: 32 channels, 16-dword rows, 4 edges/round -------
template<int HALF>
__global__ void k_agg1h(const int* __restrict__ row_start, const int* __restrict__ csr_src,
                        const unsigned int* __restrict__ h1h, const float* __restrict__ dinv,
                        const float* __restrict__ b1, unsigned int* __restrict__ out1h, int n) {
    const int t = threadIdx.x;
    const int wid = t >> 6, lane = t & 63;
    const int node = blockIdx.x * 4 + wid;
    if (node >= n) return;
    const int h4 = lane >> 4;       // edge slot 0..3
    const int c2 = lane & 15;       // dword within half-row

    int beg = row_start[node], end = row_start[node + 1];
    float alo0 = 0.f, ahi0 = 0.f, alo1 = 0.f, ahi1 = 0.f;
    {   // self term (prescaled by dinv[node]); counted once via h4==0
        unsigned int u = h1h[(size_t)node * 16 + c2];
        if (h4 == 0) { alo0 = bfLO(u); ahi0 = bfHI(u); }
    }
    for (int j = beg; j < end; j += 64) {
        int sv = (j + lane < end) ? csr_src[j + lane] : 0;
        int m  = min(64, end - j);
        for (int k = 0; k < m; k += 8) {
            int i0 = k + h4, i1 = k + 4 + h4;               // <= 63 always
            int s0 = __shfl(sv, i0), s1 = __shfl(sv, i1);
            float f0 = (i0 < m) ? 1.f : 0.f;
            float f1 = (i1 < m) ? 1.f : 0.f;
            unsigned int u0 = h1h[(size_t)s0 * 16 + c2];
            unsigned int u1 = h1h[(size_t)s1 * 16 + c2];
            alo0 = fmaf(f0, bfLO(u0), alo0); ahi0 = fmaf(f0, bfHI(u0), ahi0);
            alo1 = fmaf(f1, bfLO(u1), alo1); ahi1 = fmaf(f1, bfHI(u1), ahi1);
        }
    }
    float lo = alo0 + alo1, hi = ahi0 + ahi1;
    lo += __shfl_xor(lo, 16); hi += __shfl_xor(hi, 16);
    lo += __shfl_xor(lo, 32); hi += __shfl_xor(hi, 32);

    if (h4 == 0) {   // lanes 0-15 write
        float di = dinv[node];
        float2 bb = *(const float2*)(b1 + HALF * 32 + 2 * c2);
        float vlo = fmaxf(fmaf(di, lo, bb.x), 0.f);
        float vhi = fmaxf(fmaf(di, hi, bb.y), 0.f);
        out1h[(size_t)node * 16 + c2] = (unsigned int)f2bf(vlo) | ((unsigned int)f2bf(vhi) << 16);
    }
}

// ---------------- GEMM2 from half arrays -> two compact h2 halves (each 2 MB) ----------------
__global__ void k_gemm2(const unsigned int* __restrict__ o1lo, const unsigned int* __restrict__ o1hi,
                        const float* __restrict__ W2, const float* __restrict__ dinv,
                        unsigned int* __restrict__ h2lo, unsigned int* __restrict__ h2hi, int n) {
    __shared__ float xt[C_HID][96];        // 24 KB
    __shared__ float wl[C_HID * C_OUT];    // 10 KB
    const int t = threadIdx.x;
    const int row0 = blockIdx.x * 96;

    for (int i = t; i < C_HID * C_OUT; i += 256) wl[i] = W2[i];
    for (int idx = t; idx < 96 * 16; idx += 256) {
        int r = idx >> 4, d = idx & 15;
        int grow = row0 + r;
        unsigned int ulo = (grow < n) ? o1lo[(size_t)grow * 16 + d] : 0u;
        unsigned int uhi = (grow < n) ? o1hi[(size_t)grow * 16 + d] : 0u;
        xt[2 * d][r]      = bfLO(ulo); xt[2 * d + 1][r]  = bfHI(ulo);
        xt[32 + 2 * d][r] = bfLO(uhi); xt[33 + 2 * d][r] = bfHI(uhi);
    }
    __syncthreads();

    if (t >= 240) return;
    const int rg = t / 10, cg = t - rg * 10;   // 24 x 10
    const int r0 = rg * 4, c0 = cg * 4;
    float acc[4][4] = {};
#pragma unroll 4
    for (int k = 0; k < C_HID; ++k) {
        float4 a = *(const float4*)&xt[k][r0];
        float4 b = *(const float4*)&wl[k * C_OUT + c0];
        acc[0][0] = fmaf(a.x, b.x, acc[0][0]); acc[0][1] = fmaf(a.x, b.y, acc[0][1]);
        acc[0][2] = fmaf(a.x, b.z, acc[0][2]); acc[0][3] = fmaf(a.x, b.w, acc[0][3]);
        acc[1][0] = fmaf(a.y, b.x, acc[1][0]); acc[1][1] = fmaf(a.y, b.y, acc[1][1]);
        acc[1][2] = fmaf(a.y, b.z, acc[1][2]); acc[1][3] = fmaf(a.y, b.w, acc[1][3]);
        acc[2][0] = fmaf(a.z, b.x, acc[2][0]); acc[2][1] = fmaf(a.z, b.y, acc[2][1]);
        acc[2][2] = fmaf(a.z, b.z, acc[2][2]); acc[2][3] = fmaf(a.z, b.w, acc[2][3]);
        acc[3][0] = fmaf(a.w, b.x, acc[3][0]); acc[3][1] = fmaf(a.w, b.y, acc[3][1]);
        acc[3][2] = fmaf(a.w, b.z, acc[3][2]); acc[3][3] = fmaf(a.w, b.w, acc[3][3]);
    }
#pragma unroll
    for (int i = 0; i < 4; ++i) {
        int row = row0 + r0 + i;
        if (row < n) {
            float di = dinv[row];
            unsigned int u0 = (unsigned int)f2bf(di * acc[i][0]) | ((unsigned int)f2bf(di * acc[i][1]) << 16);
            unsigned int u1 = (unsigned int)f2bf(di * acc[i][2]) | ((unsigned int)f2bf(di * acc[i][3]) << 16);
            if (c0 < 20) {
                h2lo[(size_t)row * 10 + (c0 >> 1)]     = u0;
                h2lo[(size_t)row * 10 + (c0 >> 1) + 1] = u1;
            } else {
                h2hi[(size_t)row * 10 + ((c0 - 20) >> 1)]     = u0;
                h2hi[(size_t)row * 10 + ((c0 - 20) >> 1) + 1] = u1;
            }
        }
    }
}

// ------- layer-2 aggregate half-pass: 20 channels, 10-dword rows, 6 edges/round -------
// PASS 0: gather h2lo, write raw partial sums (float2 per dword-channel-pair).
// PASS 1: gather h2hi, combine with partials, bias + log_softmax, write out.
template<int PASS>
__global__ void k_agg2h(const int* __restrict__ row_start, const int* __restrict__ csr_src,
                        const unsigned int* __restrict__ h2h, const float* __restrict__ dinv,
                        const float* __restrict__ b2, float2* __restrict__ accLo,
                        float* __restrict__ out, int n) {
    const int t = threadIdx.x;
    const int wid = t >> 6, lane = t & 63;
    const int node = blockIdx.x * 4 + wid;
    if (node >= n) return;
    const int h6 = lane / 10;           // edge slot 0..5 (lanes 60-63: idle group 6)
    const int c2 = lane - h6 * 10;
    const bool act = h6 < 6;

    int beg = row_start[node], end = row_start[node + 1];
    float alo0 = 0.f, ahi0 = 0.f, alo1 = 0.f, ahi1 = 0.f;
    if (h6 == 0) {   // self term
        unsigned int u = h2h[(size_t)node * 10 + c2];
        alo0 = bfLO(u); ahi0 = bfHI(u);
    }
    for (int j = beg; j < end; j += 64) {
        int sv = (j + lane < end) ? csr_src[j + lane] : 0;
        int m  = min(64, end - j);
        for (int k = 0; k < m; k += 12) {
            int i0 = k + h6, i1 = k + 6 + h6;
            int s0 = __shfl(sv, i0 & 63), s1 = __shfl(sv, i1 & 63);
            float f0 = (act && i0 < m) ? 1.f : 0.f;
            float f1 = (act && i1 < m) ? 1.f : 0.f;
            unsigned int u0 = h2h[(size_t)s0 * 10 + c2];
            unsigned int u1 = h2h[(size_t)s1 * 10 + c2];
            alo0 = fmaf(f0, bfLO(u0), alo0); ahi0 = fmaf(f0, bfHI(u0), ahi0);
            alo1 = fmaf(f1, bfLO(u1), alo1); ahi1 = fmaf(f1, bfHI(u1), ahi1);
        }
    }
    float plo = alo0 + alo1, phi = ahi0 + ahi1;
    // combine the 6 slot groups -> every lane gets the total for its c2
    float lo = 0.f, hi = 0.f;
#pragma unroll
    for (int g = 0; g < 6; ++g) {
        lo += __shfl(plo, c2 + 10 * g);
        hi += __shfl(phi, c2 + 10 * g);
    }

    if (PASS == 0) {
        if (lane < 10) accLo[(size_t)node * 10 + c2] = make_float2(lo, hi);
    } else {
        float di = dinv[node];
        float vA = -INFINITY, vB = -INFINITY, vC = -INFINITY, vD = -INFINITY;
        if (lane < 10) {
            float2 p = accLo[(size_t)node * 10 + c2];
            vA = fmaf(di, p.x, b2[2 * c2]);          // ch 2c2
            vB = fmaf(di, p.y, b2[2 * c2 + 1]);      // ch 2c2+1
            vC = fmaf(di, lo,  b2[20 + 2 * c2]);     // ch 20+2c2
            vD = fmaf(di, hi,  b2[21 + 2 * c2]);     // ch 21+2c2
        }
        float mx = fmaxf(fmaxf(vA, vB), fmaxf(vC, vD));
#pragma unroll
        for (int off = 1; off <= 8; off <<= 1) mx = fmaxf(mx, __shfl_xor(mx, off));
        float es = 0.f;
        if (lane < 10)
            es = expf(vA - mx) + expf(vB - mx) + expf(vC - mx) + expf(vD - mx);
#pragma unroll
        for (int off = 1; off <= 8; off <<= 1) es += __shfl_xor(es, off);
        float lse = mx + logf(es);
        if (lane < 10) {
            *(float2*)(out + (size_t)node * C_OUT + 2 * c2)      = make_float2(vA - lse, vB - lse);
            *(float2*)(out + (size_t)node * C_OUT + 20 + 2 * c2) = make_float2(vC - lse, vD - lse);
        }
    }
}

extern "C" void kernel_launch(void* const* d_in, const int* in_sizes, int n_in,
                              void* d_out, int out_size, void* d_ws, size_t ws_size,
                              hipStream_t stream) {
    const float* X   = (const float*)d_in[0];
    const int*   src = (const int*)d_in[1];
    const int*   dst = (const int*)d_in[2];
    const float* W1  = (const float*)d_in[3];
    const float* b1  = (const float*)d_in[4];
    const float* W2  = (const float*)d_in[5];
    const float* b2  = (const float*)d_in[6];
    float* out = (float*)d_out;

    const int N = in_sizes[0] / C_IN;
    const int E = in_sizes[1];
    const int NBKT = (N + BKT_N - 1) >> BKT_SH;
    const int nchunks = (E + CHUNK - 1) / CHUNK;

    // workspace layout
    char* ws = (char*)d_ws;
    size_t off = 0;
    auto take = [&](size_t bytes) { char* p = ws + off; off = (off + bytes + 255) & ~(size_t)255; return p; };
    int*   hist2d    = (int*)  take((size_t)nchunks * NBKT * 4);
    int*   base2d    = (int*)  take((size_t)nchunks * NBKT * 4);
    int*   tot       = (int*)  take(512 * 4);
    int*   bstart    = (int*)  take(512 * 4);
    unsigned int* bpack = (unsigned int*)take((size_t)E * 4);
    int*   csr_src   = (int*)  take((size_t)E * 4);
    int*   row_start = (int*)  take((size_t)(N + 1) * 4);
    float* dinv      = (float*)take((size_t)N * 4);
    unsigned short* h1lo  = (unsigned short*)take((size_t)N * 32 * 2);   // 3.2 MB, L2-resident
    unsigned short* h1hi  = (unsigned short*)take((size_t)N * 32 * 2);
    unsigned int*   out1lo = (unsigned int*)take((size_t)N * 16 * 4);
    unsigned int*   out1hi = (unsigned int*)take((size_t)N * 16 * 4);
    unsigned int*   h2lo   = (unsigned int*)take((size_t)N * 10 * 4);    // 2 MB, L2-resident
    unsigned int*   h2hi   = (unsigned int*)take((size_t)N * 10 * 4);
    float2*         accLo  = (float2*)      take((size_t)N * 10 * 8);

    k_hist    <<<nchunks, 256, 0, stream>>>(dst, hist2d, E, NBKT);
    k_bktscan <<<NBKT, 256, 0, stream>>>(hist2d, base2d, tot, nchunks, NBKT);
    k_scan_bkt<<<1, 256, 0, stream>>>(tot, bstart, NBKT, E);
    k_binA    <<<nchunks, 256, 0, stream>>>(src, dst, bstart, hist2d, base2d, bpack, E, NBKT);
    k_binB    <<<NBKT, 256, 0, stream>>>(bstart, bpack, row_start, dinv, csr_src, N, E, NBKT);

    k_gemm1   <<<(N + 63) / 64, 256, 0, stream>>>(X, W1, dinv, h1lo, h1hi, N);
    k_agg1h<0><<<(N + 3) / 4, 256, 0, stream>>>(row_start, csr_src, (const unsigned int*)h1lo,
                                                dinv, b1, out1lo, N);
    k_agg1h<1><<<(N + 3) / 4, 256, 0, stream>>>(row_start, csr_src, (const unsigned int*)h1hi,
                                                dinv, b1, out1hi, N);
    k_gemm2   <<<(N + 95) / 96, 256, 0, stream>>>(out1lo, out1hi, W2, dinv, h2lo, h2hi, N);
    k_agg2h<0><<<(N + 3) / 4, 256, 0, stream>>>(row_start, csr_src, h2lo, dinv, b2, accLo, out, N);
    k_agg2h<1><<<(N + 3) / 4, 256, 0, stream>>>(row_start, csr_src, h2hi, dinv, b2, accLo, out, N);
}

// Round 15
// 121.489 us; speedup vs baseline: 1.2653x; 1.2653x over previous
//
#include <hip/hip_runtime.h>
#include <math.h>

#define C_IN  128
#define C_HID 64
#define C_OUT 40
#define H1DW  32                      // dwords per h1 row (64 bf16)
#define H2DW  20                      // dwords per h2 row (40 bf16)

#define BKT_SH 7
#define BKT_N  (1 << BKT_SH)          // 128 nodes per bucket
#define CHUNK  1024                   // edges per hist/binA block
#define EPT    (CHUNK / 256)          // 4 edges per thread

__device__ __forceinline__ float bf2f(unsigned short u) {
    return __uint_as_float(((unsigned int)u) << 16);
}
__device__ __forceinline__ unsigned short f2bf(float f) {   // round-to-nearest-even
    unsigned int x = __float_as_uint(f);
    return (unsigned short)((x + 0x7FFFu + ((x >> 16) & 1u)) >> 16);
}

// ---------------- pass 0: per-chunk, per-bucket histogram (no global atomics) ----------------
__global__ void k_hist(const int* __restrict__ dst, int* __restrict__ hist2d, int e, int nbkt) {
    __shared__ int hist[512];
    for (int i = threadIdx.x; i < nbkt; i += 256) hist[i] = 0;
    __syncthreads();
    int base = blockIdx.x * CHUNK;
#pragma unroll
    for (int j = 0; j < EPT; ++j) {
        int i = base + j * 256 + threadIdx.x;
        if (i < e) atomicAdd(&hist[dst[i] >> BKT_SH], 1);
    }
    __syncthreads();
    int* row = hist2d + (size_t)blockIdx.x * nbkt;
    for (int i = threadIdx.x; i < nbkt; i += 256) row[i] = hist[i];
}

// ---------------- per-bucket scan over chunks (looped, carry): base2d + tot ----------------
__global__ void k_bktscan(const int* __restrict__ hist2d, int* __restrict__ base2d,
                          int* __restrict__ tot, int nchunks, int nbkt) {
    __shared__ int wtot[4];
    const int b = blockIdx.x;
    const int t = threadIdx.x;
    const int lane = t & 63, wv = t >> 6;
    int carry = 0;
    for (int c0 = 0; c0 < nchunks; c0 += 256) {
        int c = c0 + t;
        int v = (c < nchunks) ? hist2d[(size_t)c * nbkt + b] : 0;
        int inc = v;
        for (int o = 1; o < 64; o <<= 1) { int u = __shfl_up(inc, o); if (lane >= o) inc += u; }
        if (lane == 63) wtot[wv] = inc;
        __syncthreads();
        int add = carry;
        for (int k = 0; k < wv; ++k) add += wtot[k];
        if (c < nchunks) base2d[(size_t)c * nbkt + b] = add + inc - v;
        carry += wtot[0] + wtot[1] + wtot[2] + wtot[3];
        __syncthreads();
    }
    if (t == 0) tot[b] = carry;
}

// ---------------- scan over bucket totals (looped, carry) -> bstart ----------------
__global__ void k_scan_bkt(const int* __restrict__ tot, int* __restrict__ bstart, int nbkt, int e) {
    __shared__ int wtot[4];
    const int t = threadIdx.x;
    const int lane = t & 63, wv = t >> 6;
    int carry = 0;
    for (int b0 = 0; b0 < nbkt; b0 += 256) {
        int b = b0 + t;
        int v = (b < nbkt) ? tot[b] : 0;
        int inc = v;
        for (int o = 1; o < 64; o <<= 1) { int u = __shfl_up(inc, o); if (lane >= o) inc += u; }
        if (lane == 63) wtot[wv] = inc;
        __syncthreads();
        int add = carry;
        for (int k = 0; k < wv; ++k) add += wtot[k];
        if (b < nbkt) bstart[b] = add + inc - v;
        carry += wtot[0] + wtot[1] + wtot[2] + wtot[3];
        __syncthreads();
    }
    if (t == 0) bstart[nbkt] = e;
}

// ---------------- pass A: LDS multisplit by bucket (hist reused from hist2d) ----------------
__global__ void k_binA(const int* __restrict__ src, const int* __restrict__ dst,
                       const int* __restrict__ bstart, const int* __restrict__ hist2d,
                       const int* __restrict__ base2d, unsigned int* __restrict__ bpack,
                       int e, int nbkt) {
    __shared__ int hist[512];          // local cursors
    __shared__ int excl[512];
    __shared__ int gbase[512];
    __shared__ int wtot[4];
    __shared__ unsigned int stage[CHUNK];
    const int t = threadIdx.x;
    const int base = blockIdx.x * CHUNK;
    const int lane = t & 63, wv = t >> 6;

    int carry = 0;
    for (int b0 = 0; b0 < nbkt; b0 += 256) {
        int b = b0 + t;
        int v = (b < nbkt) ? hist2d[(size_t)blockIdx.x * nbkt + b] : 0;
        int inc = v;
        for (int o = 1; o < 64; o <<= 1) { int u = __shfl_up(inc, o); if (lane >= o) inc += u; }
        if (lane == 63) wtot[wv] = inc;
        __syncthreads();
        int add = carry;
        for (int k = 0; k < wv; ++k) add += wtot[k];
        if (b < nbkt) {
            excl[b]  = add + inc - v;
            hist[b]  = 0;
            gbase[b] = bstart[b] + base2d[(size_t)blockIdx.x * nbkt + b];
        }
        carry += wtot[0] + wtot[1] + wtot[2] + wtot[3];
        __syncthreads();
    }

#pragma unroll
    for (int j = 0; j < EPT; ++j) {
        int i = base + j * 256 + t;
        if (i < e) {
            int d = dst[i];
            unsigned int pk = (unsigned int)src[i] | ((unsigned int)d << 16);   // N < 65536
            int bk = d >> BKT_SH;
            int p  = excl[bk] + atomicAdd(&hist[bk], 1);
            stage[p] = pk;
        }
    }
    __syncthreads();

    int nchunk = min(CHUNK, e - base);
    for (int i = t; i < nchunk; i += 256) {
        unsigned int u = stage[i];
        int b = (int)(u >> 16) >> BKT_SH;
        bpack[gbase[b] + (i - excl[b])] = u;
    }
}

// ---------------- pass B: per-bucket counting sort -> dinv/row_start/csr_src ----------------
__global__ void k_binB(const int* __restrict__ bstart, const unsigned int* __restrict__ bpack,
                       int* __restrict__ row_start, float* __restrict__ dinv,
                       int* __restrict__ csr_src, int n, int e, int nbkt) {
    __shared__ int hist[BKT_N];
    __shared__ int excl[BKT_N];
    __shared__ int wtot[4];
    const int t = threadIdx.x;
    const int b = blockIdx.x;
    const int beg = bstart[b], end = bstart[b + 1];
    const int nodebase = b << BKT_SH;
    const int nloc = min(BKT_N, n - nodebase);

    for (int i = t; i < nloc; i += 256) hist[i] = 0;
    __syncthreads();
    for (int i = beg + t; i < end; i += 256)
        atomicAdd(&hist[(int)(bpack[i] >> 16) - nodebase], 1);
    __syncthreads();

    {
        int idx = t;
        int v = (idx < nloc) ? hist[idx] : 0;
        int inc = v; int lane = t & 63; int wv = t >> 6;
        for (int o = 1; o < 64; o <<= 1) { int u = __shfl_up(inc, o); if (lane >= o) inc += u; }
        if (lane == 63) wtot[wv] = inc;
        __syncthreads();
        int add = 0;
        for (int k = 0; k < wv; ++k) add += wtot[k];
        if (idx < nloc) excl[idx] = add + inc - v;
    }
    __syncthreads();

    for (int i = t; i < nloc; i += 256) {
        row_start[nodebase + i] = beg + excl[i];
        dinv[nodebase + i] = rsqrtf((float)hist[i] + 1.0f);   // +1 self loop
    }
    if (b == nbkt - 1 && t == 0) row_start[n] = e;
    __syncthreads();
    for (int i = t; i < nloc; i += 256) hist[i] = 0;   // reuse as cursors
    __syncthreads();

    for (int i = beg + t; i < end; i += 256) {
        unsigned int u = bpack[i];
        int dl = (int)(u >> 16) - nodebase;
        int p = beg + excl[dl] + atomicAdd(&hist[dl], 1);
        csr_src[p] = (int)(u & 0xFFFFu);
    }
}

// ---------------- GEMM1: h1b = bf16(dinv[row] * (X @ W1))  (N x 64) ----------------
__global__ void k_gemm1(const float* __restrict__ X, const float* __restrict__ W1,
                        const float* __restrict__ dinv, unsigned short* __restrict__ h1b, int n) {
    __shared__ float xt[C_IN][64];
    __shared__ float wl[C_IN * C_HID];
    const int t = threadIdx.x;
    const int row0 = blockIdx.x * 64;

    for (int i = t; i < C_IN * C_HID; i += 256) wl[i] = W1[i];
    {
        int r = t >> 2, q = t & 3;
        int grow = row0 + r;
        for (int j = 0; j < 8; ++j) {
            int k = q * 32 + j * 4;
            float4 v = make_float4(0.f, 0.f, 0.f, 0.f);
            if (grow < n) v = *(const float4*)(X + (size_t)grow * C_IN + k);
            xt[k + 0][r] = v.x; xt[k + 1][r] = v.y; xt[k + 2][r] = v.z; xt[k + 3][r] = v.w;
        }
    }
    __syncthreads();

    const int rg = t >> 4, cg = t & 15;
    const int r0 = rg * 4, c0 = cg * 4;
    float acc[4][4] = {};
#pragma unroll 4
    for (int k = 0; k < C_IN; ++k) {
        float4 a = *(const float4*)&xt[k][r0];
        float4 b = *(const float4*)&wl[k * C_HID + c0];
        acc[0][0] = fmaf(a.x, b.x, acc[0][0]); acc[0][1] = fmaf(a.x, b.y, acc[0][1]);
        acc[0][2] = fmaf(a.x, b.z, acc[0][2]); acc[0][3] = fmaf(a.x, b.w, acc[0][3]);
        acc[1][0] = fmaf(a.y, b.x, acc[1][0]); acc[1][1] = fmaf(a.y, b.y, acc[1][1]);
        acc[1][2] = fmaf(a.y, b.z, acc[1][2]); acc[1][3] = fmaf(a.y, b.w, acc[1][3]);
        acc[2][0] = fmaf(a.z, b.x, acc[2][0]); acc[2][1] = fmaf(a.z, b.y, acc[2][1]);
        acc[2][2] = fmaf(a.z, b.z, acc[2][2]); acc[2][3] = fmaf(a.z, b.w, acc[2][3]);
        acc[3][0] = fmaf(a.w, b.x, acc[3][0]); acc[3][1] = fmaf(a.w, b.y, acc[3][1]);
        acc[3][2] = fmaf(a.w, b.z, acc[3][2]); acc[3][3] = fmaf(a.w, b.w, acc[3][3]);
    }
#pragma unroll
    for (int i = 0; i < 4; ++i) {
        int row = row0 + r0 + i;
        if (row < n) {
            float di = dinv[row];
            ushort4 o;
            o.x = f2bf(di * acc[i][0]); o.y = f2bf(di * acc[i][1]);
            o.z = f2bf(di * acc[i][2]); o.w = f2bf(di * acc[i][3]);
            *(ushort4*)(h1b + (size_t)row * C_HID + c0) = o;
        }
    }
}

// ------- fused layer-1 aggregate + bias + relu + GEMM2 (packed-dword gather) -------
// 512 threads = 8 waves = 8 nodes per block. Gather: lane = (h, c2); half h handles
// edge k+2i+h, dword c2 = channels (2c2, 2c2+1). 2 edges per wave load round.
__global__ void k_agg1g2(const int* __restrict__ row_start, const int* __restrict__ csr_src,
                         const unsigned short* __restrict__ h1b, const float* __restrict__ dinv,
                         const float* __restrict__ b1, const float* __restrict__ W2,
                         unsigned short* __restrict__ h2b, int n) {
    __shared__ float wl[C_HID * C_OUT];       // 10 KB
    __shared__ float rowbuf[8][C_HID];        // 2 KB
    const int t = threadIdx.x;
    for (int i = t; i < C_HID * C_OUT; i += 512) wl[i] = W2[i];
    __syncthreads();

    const int wid  = t >> 6;
    const int lane = t & 63;
    const int node = blockIdx.x * 8 + wid;
    if (node >= n) return;

    const int h  = lane >> 5;       // which edge of the pair
    const int c2 = lane & 31;       // dword index within row
    const unsigned int* h1d = (const unsigned int*)h1b;

    int beg = row_start[node], end = row_start[node + 1];
    float alo[4] = {0.f, 0.f, 0.f, 0.f}, ahi[4] = {0.f, 0.f, 0.f, 0.f};
    {   // self term (prescaled by dinv[node]); only half h==0 contributes
        unsigned int u = h1d[(size_t)node * H1DW + c2];
        if (h == 0) {
            alo[0] = __uint_as_float(u << 16);
            ahi[0] = __uint_as_float(u & 0xFFFF0000u);
        }
    }
    for (int j = beg; j < end; j += 64) {
        int sv = (j + lane < end) ? csr_src[j + lane] : 0;
        int m  = min(64, end - j);
        for (int k = 0; k < m; k += 8) {
#pragma unroll
            for (int i = 0; i < 4; ++i) {
                int idx = k + 2 * i + h;                 // <= 63 always
                int s   = __shfl(sv, idx);
                float f = (idx < m) ? 1.f : 0.f;
                unsigned int u = h1d[(size_t)s * H1DW + c2];
                alo[i] = fmaf(f, __uint_as_float(u << 16), alo[i]);
                ahi[i] = fmaf(f, __uint_as_float(u & 0xFFFF0000u), ahi[i]);
            }
        }
    }
    float lo = (alo[0] + alo[1]) + (alo[2] + alo[3]);
    float hi = (ahi[0] + ahi[1]) + (ahi[2] + ahi[3]);
    lo += __shfl_xor(lo, 32);                            // combine halves
    hi += __shfl_xor(hi, 32);

    float di = dinv[node];
    if (h == 0) {                                        // lanes 0-31: bias + relu -> rowbuf
        float2 bb = *(const float2*)(b1 + 2 * c2);
        float vlo = di * lo + bb.x;
        float vhi = di * hi + bb.y;
        rowbuf[wid][2 * c2]     = vlo > 0.f ? vlo : 0.f;
        rowbuf[wid][2 * c2 + 1] = vhi > 0.f ? vhi : 0.f;
    }
    // matvec (same-wave RAW on rowbuf): h2[c] = sum_k row[k]*W2[k][c]
    if (lane < C_OUT) {
        float acc2 = 0.f;
#pragma unroll 8
        for (int k = 0; k < C_HID; ++k)
            acc2 = fmaf(rowbuf[wid][k], wl[k * C_OUT + lane], acc2);
        h2b[(size_t)node * C_OUT + lane] = f2bf(di * acc2);
    }
}

// ------- layer-2 aggregate + bias + log_softmax (packed-dword gather, 3 edges/round) -------
// lane = (h3, c2): h3 = lane/20 in {0,1,2} (lanes 60-63 discarded), c2 = dword 0..19.
__global__ void k_agg2(const int* __restrict__ row_start, const int* __restrict__ csr_src,
                       const unsigned short* __restrict__ h2b, const float* __restrict__ dinv,
                       const float* __restrict__ b2, float* __restrict__ out, int n) {
    int node = (blockIdx.x * 256 + threadIdx.x) >> 6;
    int lane = threadIdx.x & 63;
    if (node >= n) return;
    const int h3 = lane / 20;
    const int c2 = lane - h3 * 20;
    const unsigned int* h2d = (const unsigned int*)h2b;

    int beg = row_start[node], end = row_start[node + 1];
    float alo[4] = {0.f, 0.f, 0.f, 0.f}, ahi[4] = {0.f, 0.f, 0.f, 0.f};
    if (h3 == 0) {   // self term
        unsigned int u = h2d[(size_t)node * H2DW + c2];
        alo[0] = __uint_as_float(u << 16);
        ahi[0] = __uint_as_float(u & 0xFFFF0000u);
    }
    for (int j = beg; j < end; j += 64) {
        int sv = (j + lane < end) ? csr_src[j + lane] : 0;
        int m = min(64, end - j);
        for (int k = 0; k < m; k += 12) {
#pragma unroll
            for (int i = 0; i < 4; ++i) {
                int idx = k + 3 * i + h3;
                int s = __shfl(sv, idx & 63);
                float f = (idx < m) ? 1.f : 0.f;        // h3==3 lanes' results are discarded
                unsigned int u = h2d[(size_t)s * H2DW + c2];
                alo[i] = fmaf(f, __uint_as_float(u << 16), alo[i]);
                ahi[i] = fmaf(f, __uint_as_float(u & 0xFFFF0000u), ahi[i]);
            }
        }
    }
    float lo = (alo[0] + alo[1]) + (alo[2] + alo[3]);
    float hi = (ahi[0] + ahi[1]) + (ahi[2] + ahi[3]);
    // combine thirds: lanes 0-19 pick up partials from lanes c2+20 (h3=1), c2+40 (h3=2)
    float lA = __shfl(lo, c2 + 20), lB = __shfl(lo, c2 + 40);
    float hA = __shfl(hi, c2 + 20), hB = __shfl(hi, c2 + 40);
    lo += lA + lB;
    hi += hA + hB;

    float di = dinv[node];
    float vlo = -INFINITY, vhi = -INFINITY, ex = 0.f;
    if (h3 == 0) {
        float2 bb = *(const float2*)(b2 + 2 * c2);
        vlo = di * lo + bb.x;
        vhi = di * hi + bb.y;
    }
    float mx = fmaxf(vlo, vhi);
    for (int off = 16; off; off >>= 1) mx = fmaxf(mx, __shfl_xor(mx, off));
    if (h3 == 0) ex = expf(vlo - mx) + expf(vhi - mx);
    float ss = ex;
    for (int off = 16; off; off >>= 1) ss += __shfl_xor(ss, off);
    float lse = mx + logf(ss);
    if (h3 == 0)
        *(float2*)(out + (size_t)node * C_OUT + 2 * c2) = make_float2(vlo - lse, vhi - lse);
}

extern "C" void kernel_launch(void* const* d_in, const int* in_sizes, int n_in,
                              void* d_out, int out_size, void* d_ws, size_t ws_size,
                              hipStream_t stream) {
    const float* X   = (const float*)d_in[0];
    const int*   src = (const int*)d_in[1];
    const int*   dst = (const int*)d_in[2];
    const float* W1  = (const float*)d_in[3];
    const float* b1  = (const float*)d_in[4];
    const float* W2  = (const float*)d_in[5];
    const float* b2  = (const float*)d_in[6];
    float* out = (float*)d_out;

    const int N = in_sizes[0] / C_IN;
    const int E = in_sizes[1];
    const int NBKT = (N + BKT_N - 1) >> BKT_SH;
    const int nchunks = (E + CHUNK - 1) / CHUNK;

    // workspace layout
    char* ws = (char*)d_ws;
    size_t off = 0;
    auto take = [&](size_t bytes) { char* p = ws + off; off = (off + bytes + 255) & ~(size_t)255; return p; };
    int*   hist2d    = (int*)  take((size_t)nchunks * NBKT * 4);
    int*   base2d    = (int*)  take((size_t)nchunks * NBKT * 4);
    int*   tot       = (int*)  take(512 * 4);
    int*   bstart    = (int*)  take(512 * 4);
    unsigned int* bpack = (unsigned int*)take((size_t)E * 4);
    int*   csr_src   = (int*)  take((size_t)E * 4);
    int*   row_start = (int*)  take((size_t)(N + 1) * 4);
    float* dinv      = (float*)take((size_t)N * 4);
    unsigned short* h1b = (unsigned short*)take((size_t)N * C_HID * 2);
    unsigned short* h2b = (unsigned short*)take((size_t)N * H2DW * 2 * 2);

    k_hist    <<<nchunks, 256, 0, stream>>>(dst, hist2d, E, NBKT);
    k_bktscan <<<NBKT, 256, 0, stream>>>(hist2d, base2d, tot, nchunks, NBKT);
    k_scan_bkt<<<1, 256, 0, stream>>>(tot, bstart, NBKT, E);
    k_binA    <<<nchunks, 256, 0, stream>>>(src, dst, bstart, hist2d, base2d, bpack, E, NBKT);
    k_binB    <<<NBKT, 256, 0, stream>>>(bstart, bpack, row_start, dinv, csr_src, N, E, NBKT);

    k_gemm1   <<<(N + 63) / 64, 256, 0, stream>>>(X, W1, dinv, h1b, N);
    k_agg1g2  <<<(N + 7) / 8, 512, 0, stream>>>(row_start, csr_src, h1b, dinv, b1, W2, h2b, N);
    k_agg2    <<<((size_t)N * 64 + 255) / 256, 256, 0, stream>>>(row_start, csr_src, h2b,
                                                                 dinv, b2, out, N);
}

// Round 16
// 113.531 us; speedup vs baseline: 1.3540x; 1.0701x over previous
//
#include <hip/hip_runtime.h>
#include <math.h>

#define C_IN  128
#define C_HID 64
#define C_OUT 40
#define H1DW  32                      // dwords per h1 row (64 bf16)
#define H2DW  20                      // dwords per h2 row (40 bf16)

#define BKT_SH 7
#define BKT_N  (1 << BKT_SH)          // 128 nodes per bucket
#define CHUNK  1024                   // edges per hist/binA block
#define EPT    (CHUNK / 256)          // 4 edges per thread

using bf16x8 = __attribute__((ext_vector_type(8))) short;
using f32x4  = __attribute__((ext_vector_type(4))) float;

__device__ __forceinline__ float bf2f(unsigned short u) {
    return __uint_as_float(((unsigned int)u) << 16);
}
__device__ __forceinline__ unsigned short f2bf(float f) {   // round-to-nearest-even
    unsigned int x = __float_as_uint(f);
    return (unsigned short)((x + 0x7FFFu + ((x >> 16) & 1u)) >> 16);
}

// ---------------- pass 0: per-chunk, per-bucket histogram (no global atomics) ----------------
__global__ void k_hist(const int* __restrict__ dst, int* __restrict__ hist2d, int e, int nbkt) {
    __shared__ int hist[512];
    for (int i = threadIdx.x; i < nbkt; i += 256) hist[i] = 0;
    __syncthreads();
    int base = blockIdx.x * CHUNK;
#pragma unroll
    for (int j = 0; j < EPT; ++j) {
        int i = base + j * 256 + threadIdx.x;
        if (i < e) atomicAdd(&hist[dst[i] >> BKT_SH], 1);
    }
    __syncthreads();
    int* row = hist2d + (size_t)blockIdx.x * nbkt;
    for (int i = threadIdx.x; i < nbkt; i += 256) row[i] = hist[i];
}

// ---------------- per-bucket scan over chunks (looped, carry): base2d + tot ----------------
__global__ void k_bktscan(const int* __restrict__ hist2d, int* __restrict__ base2d,
                          int* __restrict__ tot, int nchunks, int nbkt) {
    __shared__ int wtot[4];
    const int b = blockIdx.x;
    const int t = threadIdx.x;
    const int lane = t & 63, wv = t >> 6;
    int carry = 0;
    for (int c0 = 0; c0 < nchunks; c0 += 256) {
        int c = c0 + t;
        int v = (c < nchunks) ? hist2d[(size_t)c * nbkt + b] : 0;
        int inc = v;
        for (int o = 1; o < 64; o <<= 1) { int u = __shfl_up(inc, o); if (lane >= o) inc += u; }
        if (lane == 63) wtot[wv] = inc;
        __syncthreads();
        int add = carry;
        for (int k = 0; k < wv; ++k) add += wtot[k];
        if (c < nchunks) base2d[(size_t)c * nbkt + b] = add + inc - v;
        carry += wtot[0] + wtot[1] + wtot[2] + wtot[3];
        __syncthreads();
    }
    if (t == 0) tot[b] = carry;
}

// ---------------- scan over bucket totals (looped, carry) -> bstart ----------------
__global__ void k_scan_bkt(const int* __restrict__ tot, int* __restrict__ bstart, int nbkt, int e) {
    __shared__ int wtot[4];
    const int t = threadIdx.x;
    const int lane = t & 63, wv = t >> 6;
    int carry = 0;
    for (int b0 = 0; b0 < nbkt; b0 += 256) {
        int b = b0 + t;
        int v = (b < nbkt) ? tot[b] : 0;
        int inc = v;
        for (int o = 1; o < 64; o <<= 1) { int u = __shfl_up(inc, o); if (lane >= o) inc += u; }
        if (lane == 63) wtot[wv] = inc;
        __syncthreads();
        int add = carry;
        for (int k = 0; k < wv; ++k) add += wtot[k];
        if (b < nbkt) bstart[b] = add + inc - v;
        carry += wtot[0] + wtot[1] + wtot[2] + wtot[3];
        __syncthreads();
    }
    if (t == 0) bstart[nbkt] = e;
}

// ---------------- pass A: LDS multisplit by bucket (hist reused from hist2d) ----------------
__global__ void k_binA(const int* __restrict__ src, const int* __restrict__ dst,
                       const int* __restrict__ bstart, const int* __restrict__ hist2d,
                       const int* __restrict__ base2d, unsigned int* __restrict__ bpack,
                       int e, int nbkt) {
    __shared__ int hist[512];          // local cursors
    __shared__ int excl[512];
    __shared__ int gbase[512];
    __shared__ int wtot[4];
    __shared__ unsigned int stage[CHUNK];
    const int t = threadIdx.x;
    const int base = blockIdx.x * CHUNK;
    const int lane = t & 63, wv = t >> 6;

    int carry = 0;
    for (int b0 = 0; b0 < nbkt; b0 += 256) {
        int b = b0 + t;
        int v = (b < nbkt) ? hist2d[(size_t)blockIdx.x * nbkt + b] : 0;
        int inc = v;
        for (int o = 1; o < 64; o <<= 1) { int u = __shfl_up(inc, o); if (lane >= o) inc += u; }
        if (lane == 63) wtot[wv] = inc;
        __syncthreads();
        int add = carry;
        for (int k = 0; k < wv; ++k) add += wtot[k];
        if (b < nbkt) {
            excl[b]  = add + inc - v;
            hist[b]  = 0;
            gbase[b] = bstart[b] + base2d[(size_t)blockIdx.x * nbkt + b];
        }
        carry += wtot[0] + wtot[1] + wtot[2] + wtot[3];
        __syncthreads();
    }

#pragma unroll
    for (int j = 0; j < EPT; ++j) {
        int i = base + j * 256 + t;
        if (i < e) {
            int d = dst[i];
            unsigned int pk = (unsigned int)src[i] | ((unsigned int)d << 16);   // N < 65536
            int bk = d >> BKT_SH;
            int p  = excl[bk] + atomicAdd(&hist[bk], 1);
            stage[p] = pk;
        }
    }
    __syncthreads();

    int nchunk = min(CHUNK, e - base);
    for (int i = t; i < nchunk; i += 256) {
        unsigned int u = stage[i];
        int b = (int)(u >> 16) >> BKT_SH;
        bpack[gbase[b] + (i - excl[b])] = u;
    }
}

// ---------------- pass B: per-bucket counting sort -> dinv/row_start/csr_src ----------------
__global__ void k_binB(const int* __restrict__ bstart, const unsigned int* __restrict__ bpack,
                       int* __restrict__ row_start, float* __restrict__ dinv,
                       int* __restrict__ csr_src, int n, int e, int nbkt) {
    __shared__ int hist[BKT_N];
    __shared__ int excl[BKT_N];
    __shared__ int wtot[4];
    const int t = threadIdx.x;
    const int b = blockIdx.x;
    const int beg = bstart[b], end = bstart[b + 1];
    const int nodebase = b << BKT_SH;
    const int nloc = min(BKT_N, n - nodebase);

    for (int i = t; i < nloc; i += 256) hist[i] = 0;
    __syncthreads();
    for (int i = beg + t; i < end; i += 256)
        atomicAdd(&hist[(int)(bpack[i] >> 16) - nodebase], 1);
    __syncthreads();

    {
        int idx = t;
        int v = (idx < nloc) ? hist[idx] : 0;
        int inc = v; int lane = t & 63; int wv = t >> 6;
        for (int o = 1; o < 64; o <<= 1) { int u = __shfl_up(inc, o); if (lane >= o) inc += u; }
        if (lane == 63) wtot[wv] = inc;
        __syncthreads();
        int add = 0;
        for (int k = 0; k < wv; ++k) add += wtot[k];
        if (idx < nloc) excl[idx] = add + inc - v;
    }
    __syncthreads();

    for (int i = t; i < nloc; i += 256) {
        row_start[nodebase + i] = beg + excl[i];
        dinv[nodebase + i] = rsqrtf((float)hist[i] + 1.0f);   // +1 self loop
    }
    if (b == nbkt - 1 && t == 0) row_start[n] = e;
    __syncthreads();
    for (int i = t; i < nloc; i += 256) hist[i] = 0;   // reuse as cursors
    __syncthreads();

    for (int i = beg + t; i < end; i += 256) {
        unsigned int u = bpack[i];
        int dl = (int)(u >> 16) - nodebase;
        int p = beg + excl[dl] + atomicAdd(&hist[dl], 1);
        csr_src[p] = (int)(u & 0xFFFFu);
    }
}

// ---------------- GEMM1 (MFMA): h1b = bf16(dinv[row] * (X @ W1))  (N x 64) ----------------
// 64-row x 64-col tile; 4 waves; each wave = 16 rows x 64 cols via 4 col-tiles of
// mfma_f32_16x16x32_bf16, K=128 in 4 steps. X-tile and W1^T staged in LDS as bf16,
// rows padded to 136 elements (272 B -> 2-way bank aliasing only).
__global__ void k_gemm1(const float* __restrict__ X, const float* __restrict__ W1,
                        const float* __restrict__ dinv, unsigned short* __restrict__ h1b, int n) {
    __shared__ unsigned short xb[64][136];   // A tile:  xb[r][k]   (17 KB)
    __shared__ unsigned short wt[64][136];   // B tile:  wt[c][k] = W1^T (17 KB)
    const int t = threadIdx.x;
    const int row0 = blockIdx.x * 64;

    // stage W1^T (coalesced f32 read k-major, scattered bf16 LDS write)
    for (int idx = t; idx < C_IN * C_HID; idx += 256) {
        int k = idx >> 6, c = idx & 63;
        wt[c][k] = f2bf(W1[idx]);
    }
    // stage X rows as bf16
    {
        int r = t >> 2, q = t & 3;
        int grow = row0 + r;
        for (int j = 0; j < 8; ++j) {
            int k = q * 32 + j * 4;
            float4 v = make_float4(0.f, 0.f, 0.f, 0.f);
            if (grow < n) v = *(const float4*)(X + (size_t)grow * C_IN + k);
            xb[r][k + 0] = f2bf(v.x); xb[r][k + 1] = f2bf(v.y);
            xb[r][k + 2] = f2bf(v.z); xb[r][k + 3] = f2bf(v.w);
        }
    }
    __syncthreads();

    const int wid  = t >> 6;
    const int lane = t & 63;
    const int r0   = wid * 16;                 // wave's row sub-tile
    const int arow = r0 + (lane & 15);
    const int kgrp = (lane >> 4) * 8;          // k offset within 32-step

    f32x4 acc[4] = {{0.f,0.f,0.f,0.f},{0.f,0.f,0.f,0.f},{0.f,0.f,0.f,0.f},{0.f,0.f,0.f,0.f}};
#pragma unroll
    for (int ks = 0; ks < C_IN; ks += 32) {
        bf16x8 a = *(const bf16x8*)&xb[arow][ks + kgrp];
#pragma unroll
        for (int ct = 0; ct < 4; ++ct) {
            bf16x8 b = *(const bf16x8*)&wt[ct * 16 + (lane & 15)][ks + kgrp];
            acc[ct] = __builtin_amdgcn_mfma_f32_16x16x32_bf16(a, b, acc[ct], 0, 0, 0);
        }
    }

    // C/D layout (m89-verified): col = lane&15, row = 4*(lane>>4)+reg
    float di[4];
    int rbase = row0 + r0 + (lane >> 4) * 4;
#pragma unroll
    for (int reg = 0; reg < 4; ++reg)
        di[reg] = (rbase + reg < n) ? dinv[rbase + reg] : 0.f;
#pragma unroll
    for (int ct = 0; ct < 4; ++ct) {
        int col = ct * 16 + (lane & 15);
#pragma unroll
        for (int reg = 0; reg < 4; ++reg) {
            int grow = rbase + reg;
            if (grow < n)
                h1b[(size_t)grow * C_HID + col] = f2bf(di[reg] * acc[ct][reg]);
        }
    }
}

// ------- fused layer-1 aggregate + bias + relu + GEMM2 (packed-dword gather) -------
// 512 threads = 8 waves = 8 nodes per block. Gather: lane = (h, c2); half h handles
// edge k+2i+h, dword c2 = channels (2c2, 2c2+1). 2 edges per wave load round.
__global__ void k_agg1g2(const int* __restrict__ row_start, const int* __restrict__ csr_src,
                         const unsigned short* __restrict__ h1b, const float* __restrict__ dinv,
                         const float* __restrict__ b1, const float* __restrict__ W2,
                         unsigned short* __restrict__ h2b, int n) {
    __shared__ float wl[C_HID * C_OUT];       // 10 KB
    __shared__ float rowbuf[8][C_HID];        // 2 KB
    const int t = threadIdx.x;
    for (int i = t; i < C_HID * C_OUT; i += 512) wl[i] = W2[i];
    __syncthreads();

    const int wid  = t >> 6;
    const int lane = t & 63;
    const int node = blockIdx.x * 8 + wid;
    if (node >= n) return;

    const int h  = lane >> 5;       // which edge of the pair
    const int c2 = lane & 31;       // dword index within row
    const unsigned int* h1d = (const unsigned int*)h1b;

    int beg = row_start[node], end = row_start[node + 1];
    float alo[4] = {0.f, 0.f, 0.f, 0.f}, ahi[4] = {0.f, 0.f, 0.f, 0.f};
    {   // self term (prescaled by dinv[node]); only half h==0 contributes
        unsigned int u = h1d[(size_t)node * H1DW + c2];
        if (h == 0) {
            alo[0] = __uint_as_float(u << 16);
            ahi[0] = __uint_as_float(u & 0xFFFF0000u);
        }
    }
    for (int j = beg; j < end; j += 64) {
        int sv = (j + lane < end) ? csr_src[j + lane] : 0;
        int m  = min(64, end - j);
        for (int k = 0; k < m; k += 8) {
#pragma unroll
            for (int i = 0; i < 4; ++i) {
                int idx = k + 2 * i + h;                 // <= 63 always
                int s   = __shfl(sv, idx);
                float f = (idx < m) ? 1.f : 0.f;
                unsigned int u = h1d[(size_t)s * H1DW + c2];
                alo[i] = fmaf(f, __uint_as_float(u << 16), alo[i]);
                ahi[i] = fmaf(f, __uint_as_float(u & 0xFFFF0000u), ahi[i]);
            }
        }
    }
    float lo = (alo[0] + alo[1]) + (alo[2] + alo[3]);
    float hi = (ahi[0] + ahi[1]) + (ahi[2] + ahi[3]);
    lo += __shfl_xor(lo, 32);                            // combine halves
    hi += __shfl_xor(hi, 32);

    float di = dinv[node];
    if (h == 0) {                                        // lanes 0-31: bias + relu -> rowbuf
        float2 bb = *(const float2*)(b1 + 2 * c2);
        float vlo = di * lo + bb.x;
        float vhi = di * hi + bb.y;
        rowbuf[wid][2 * c2]     = vlo > 0.f ? vlo : 0.f;
        rowbuf[wid][2 * c2 + 1] = vhi > 0.f ? vhi : 0.f;
    }
    // matvec (same-wave RAW on rowbuf): h2[c] = sum_k row[k]*W2[k][c]
    if (lane < C_OUT) {
        float acc2 = 0.f;
#pragma unroll 8
        for (int k = 0; k < C_HID; ++k)
            acc2 = fmaf(rowbuf[wid][k], wl[k * C_OUT + lane], acc2);
        h2b[(size_t)node * C_OUT + lane] = f2bf(di * acc2);
    }
}

// ------- layer-2 aggregate + bias + log_softmax (packed-dword gather, 3 edges/round) -------
// lane = (h3, c2): h3 = lane/20 in {0,1,2} (lanes 60-63 discarded), c2 = dword 0..19.
__global__ void k_agg2(const int* __restrict__ row_start, const int* __restrict__ csr_src,
                       const unsigned short* __restrict__ h2b, const float* __restrict__ dinv,
                       const float* __restrict__ b2, float* __restrict__ out, int n) {
    int node = (blockIdx.x * 256 + threadIdx.x) >> 6;
    int lane = threadIdx.x & 63;
    if (node >= n) return;
    const int h3 = lane / 20;
    const int c2 = lane - h3 * 20;
    const unsigned int* h2d = (const unsigned int*)h2b;

    int beg = row_start[node], end = row_start[node + 1];
    float alo[4] = {0.f, 0.f, 0.f, 0.f}, ahi[4] = {0.f, 0.f, 0.f, 0.f};
    if (h3 == 0) {   // self term
        unsigned int u = h2d[(size_t)node * H2DW + c2];
        alo[0] = __uint_as_float(u << 16);
        ahi[0] = __uint_as_float(u & 0xFFFF0000u);
    }
    for (int j = beg; j < end; j += 64) {
        int sv = (j + lane < end) ? csr_src[j + lane] : 0;
        int m = min(64, end - j);
        for (int k = 0; k < m; k += 12) {
#pragma unroll
            for (int i = 0; i < 4; ++i) {
                int idx = k + 3 * i + h3;
                int s = __shfl(sv, idx & 63);
                float f = (idx < m) ? 1.f : 0.f;        // h3==3 lanes' results are discarded
                unsigned int u = h2d[(size_t)s * H2DW + c2];
                alo[i] = fmaf(f, __uint_as_float(u << 16), alo[i]);
                ahi[i] = fmaf(f, __uint_as_float(u & 0xFFFF0000u), ahi[i]);
            }
        }
    }
    float lo = (alo[0] + alo[1]) + (alo[2] + alo[3]);
    float hi = (ahi[0] + ahi[1]) + (ahi[2] + ahi[3]);
    // combine thirds: lanes 0-19 pick up partials from lanes c2+20 (h3=1), c2+40 (h3=2)
    float lA = __shfl(lo, c2 + 20), lB = __shfl(lo, c2 + 40);
    float hA = __shfl(hi, c2 + 20), hB = __shfl(hi, c2 + 40);
    lo += lA + lB;
    hi += hA + hB;

    float di = dinv[node];
    float vlo = -INFINITY, vhi = -INFINITY, ex = 0.f;
    if (h3 == 0) {
        float2 bb = *(const float2*)(b2 + 2 * c2);
        vlo = di * lo + bb.x;
        vhi = di * hi + bb.y;
    }
    float mx = fmaxf(vlo, vhi);
    for (int off = 16; off; off >>= 1) mx = fmaxf(mx, __shfl_xor(mx, off));
    if (h3 == 0) ex = expf(vlo - mx) + expf(vhi - mx);
    float ss = ex;
    for (int off = 16; off; off >>= 1) ss += __shfl_xor(ss, off);
    float lse = mx + logf(ss);
    if (h3 == 0)
        *(float2*)(out + (size_t)node * C_OUT + 2 * c2) = make_float2(vlo - lse, vhi - lse);
}

extern "C" void kernel_launch(void* const* d_in, const int* in_sizes, int n_in,
                              void* d_out, int out_size, void* d_ws, size_t ws_size,
                              hipStream_t stream) {
    const float* X   = (const float*)d_in[0];
    const int*   src = (const int*)d_in[1];
    const int*   dst = (const int*)d_in[2];
    const float* W1  = (const float*)d_in[3];
    const float* b1  = (const float*)d_in[4];
    const float* W2  = (const float*)d_in[5];
    const float* b2  = (const float*)d_in[6];
    float* out = (float*)d_out;

    const int N = in_sizes[0] / C_IN;
    const int E = in_sizes[1];
    const int NBKT = (N + BKT_N - 1) >> BKT_SH;
    const int nchunks = (E + CHUNK - 1) / CHUNK;

    // workspace layout
    char* ws = (char*)d_ws;
    size_t off = 0;
    auto take = [&](size_t bytes) { char* p = ws + off; off = (off + bytes + 255) & ~(size_t)255; return p; };
    int*   hist2d    = (int*)  take((size_t)nchunks * NBKT * 4);
    int*   base2d    = (int*)  take((size_t)nchunks * NBKT * 4);
    int*   tot       = (int*)  take(512 * 4);
    int*   bstart    = (int*)  take(512 * 4);
    unsigned int* bpack = (unsigned int*)take((size_t)E * 4);
    int*   csr_src   = (int*)  take((size_t)E * 4);
    int*   row_start = (int*)  take((size_t)(N + 1) * 4);
    float* dinv      = (float*)take((size_t)N * 4);
    unsigned short* h1b = (unsigned short*)take((size_t)N * C_HID * 2);
    unsigned short* h2b = (unsigned short*)take((size_t)N * H2DW * 2 * 2);

    k_hist    <<<nchunks, 256, 0, stream>>>(dst, hist2d, E, NBKT);
    k_bktscan <<<NBKT, 256, 0, stream>>>(hist2d, base2d, tot, nchunks, NBKT);
    k_scan_bkt<<<1, 256, 0, stream>>>(tot, bstart, NBKT, E);
    k_binA    <<<nchunks, 256, 0, stream>>>(src, dst, bstart, hist2d, base2d, bpack, E, NBKT);
    k_binB    <<<NBKT, 256, 0, stream>>>(bstart, bpack, row_start, dinv, csr_src, N, E, NBKT);

    k_gemm1   <<<(N + 63) / 64, 256, 0, stream>>>(X, W1, dinv, h1b, N);
    k_agg1g2  <<<(N + 7) / 8, 512, 0, stream>>>(row_start, csr_src, h1b, dinv, b1, W2, h2b, N);
    k_agg2    <<<((size_t)N * 64 + 255) / 256, 256, 0, stream>>>(row_start, csr_src, h2b,
                                                                 dinv, b2, out, N);
}